// Round 1
// 546.622 us; speedup vs baseline: 1.2823x; 1.2823x over previous
//
#include <hip/hip_runtime.h>
#include <stdint.h>

#define K_DIM 4096
#define N_DIM 4096
#define M_DIM 8192

// GEMM tile geometry (3-buffer counted-vmcnt pipeline)
#define BM 256
#define BN 128
#define BK 64
#define NT (K_DIM / BK)          // 64 K-tiles

typedef __bf16 bf16x8 __attribute__((ext_vector_type(8)));
typedef float floatx4 __attribute__((ext_vector_type(4)));

// Device-global scratch (module .bss; no host symbol lookup, no ws_size assumption)
__device__ __attribute__((aligned(256))) __bf16 g_Bt[(size_t)N_DIM * K_DIM]; // W'^T [N][K]
__device__ __attribute__((aligned(256))) __bf16 g_X [(size_t)M_DIM * K_DIM]; // x as bf16 (only if mode!=0)
__device__ int g_flags[2]; // [0]: x dtype 0=bf16 1=f32 2=fp16 ; [1]: perm is candB

__device__ __forceinline__ void global_to_lds16(const void* g, void* l) {
    // width=16 async global->LDS; LDS dest = wave-uniform base + lane*16 (linear!)
    __builtin_amdgcn_global_load_lds(
        (const __attribute__((address_space(1))) uint32_t*)g,
        (__attribute__((address_space(3))) uint32_t*)l,
        16, 0, 0);
}

#define LDS_FENCE() asm volatile("" ::: "memory")

// ---------------- probe: classify dtypes / disambiguate same-size inputs ----------------
__global__ void probe_kernel(const void* xraw, const int* candA, const int* candB) {
    __shared__ int s_insane, s_small, s_badA, s_badB;
    if (threadIdx.x == 0) { s_insane = 0; s_small = 0; s_badA = 0; s_badB = 0; }
    __syncthreads();
    const uint16_t* xw = (const uint16_t*)xraw;
    int insane = 0, small = 0;
    for (int i = threadIdx.x; i < 8192; i += 256) {
        uint16_t a = (uint16_t)(xw[2 * i] & 0x7FFF);   // EVEN 16-bit words of x
        if (a >= 0x4300) insane++;                     // f32 mantissa junk ~48%; bf16 N(0,1) ~0
        if (a > 0 && a < 0x3000) small++;              // fp16 N(0,1) ~10%; bf16 ~0
    }
    int badA = 0, badB = 0;
    for (int i = threadIdx.x; i < 4096; i += 256) {
        if ((unsigned)candA[i] >= 4096u) badA++;       // permutation: all in [0,4096)
        if ((unsigned)candB[i] >= 4096u) badB++;
    }
    atomicAdd(&s_insane, insane); atomicAdd(&s_small, small);
    atomicAdd(&s_badA, badA);     atomicAdd(&s_badB, badB);
    __syncthreads();
    if (threadIdx.x == 0) {
        int mode = 0;
        if (s_insane > 32) mode = 1;          // float32
        else if (s_small > 100) mode = 2;     // float16
        g_flags[0] = mode;
        g_flags[1] = (s_badA > 0 && s_badB == 0) ? 1 : 0;
    }
}

// ---------------- normalize x -> bf16 g_X (skipped when x is already bf16) ----------------
__global__ void __launch_bounds__(256) convert_x_kernel(const void* xraw) {
    const int mode = g_flags[0];
    if (mode == 0) return;                    // data-dependent, deterministic per call
    const size_t nchunk = (size_t)M_DIM * K_DIM / 8;
    for (size_t c = (size_t)blockIdx.x * 256 + threadIdx.x; c < nchunk;
         c += (size_t)gridDim.x * 256) {
        size_t base = c * 8;
        bf16x8 o;
        if (mode == 1) {
            const float* xf = (const float*)xraw;
#pragma unroll
            for (int u = 0; u < 8; ++u) o[u] = (__bf16)xf[base + u];
        } else {
            const _Float16* xh = (const _Float16*)xraw;
#pragma unroll
            for (int u = 0; u < 8; ++u) o[u] = (__bf16)(float)xh[base + u];
        }
        *(bf16x8*)(g_X + base) = o;
    }
}

// ---------------- dequant + K-perm folded into weights ----------------
// g_Bt[n][j] = (w4(k,n)-8) * (s4(g,n)+1)^2 * (smax[g]/256),  k = q_invperm[j]
// Lane remap vs previous round: lanes = 16 n x 4 jp, so the 16 lanes sharing a
// j-pack read CONTIGUOUS n of the same q_weight row -> 1 fully-used 64B line
// instead of 64 scattered lines per unpack step (gather was the 240us cost).
__global__ void __launch_bounds__(256) dequant_perm_kernel(
    const int* __restrict__ q_weight,        // [K/8][N]
    const int* __restrict__ q_scale,         // [G][N/8]
    const void* __restrict__ qsm_raw,        // [G] (dtype per flag)
    const int* __restrict__ candA, const int* __restrict__ candB)
{
    const int mode = g_flags[0];
    const int* q_invperm = g_flags[1] ? candB : candA;

    const int n  = blockIdx.x * 16 + (threadIdx.x & 15);   // fast: contiguous n per 16 lanes
    const int jp = blockIdx.y * 16 + (threadIdx.x >> 4);   // j-pack (8 outputs)
    const int j0 = jp << 3;

    int4 ip0 = *(const int4*)(q_invperm + j0);             // broadcast within 16-lane group
    int4 ip1 = *(const int4*)(q_invperm + j0 + 4);
    int ks[8] = {ip0.x, ip0.y, ip0.z, ip0.w, ip1.x, ip1.y, ip1.z, ip1.w};

    const int nshift = (n & 7) << 2;
    const int scol = n >> 3;

    bf16x8 ov;
#pragma unroll
    for (int u = 0; u < 8; ++u) {
        int k = ks[u] & (K_DIM - 1);               // defensive clamp
        int w4 = (q_weight[(size_t)(k >> 3) * N_DIM + n] >> ((k & 7) << 2)) & 0xF;
        int g = k >> 7;
        int s4 = (q_scale[g * (N_DIM / 8) + scol] >> nshift) & 0xF;
        float smax;
        if (mode == 1)      smax = ((const float*)qsm_raw)[g];
        else if (mode == 2) smax = (float)((const _Float16*)qsm_raw)[g];
        else                smax = (float)((const __bf16*)qsm_raw)[g];
        float sp1 = (float)(s4 + 1);
        float w = (float)(w4 - 8) * (sp1 * sp1 * smax * (1.0f / 256.0f));
        ov[u] = (__bf16)w;
    }
    *(bf16x8*)(g_Bt + (size_t)n * K_DIM + j0) = ov;
}

// ---------------- bf16 GEMM: C = X * g_Bt^T + bias ----------------
// 256x128 tile, BK=64, 8 waves (4M x 2N of 64x64), 3-deep LDS pipeline:
// stage tile t+2 while computing tile t, steady-state s_waitcnt vmcnt(6)
// (never 0 in main loop). LDS XOR-swizzle (kelem ^= (row&7)<<3) applied via
// linear gload_lds dest + inverse-swizzled GLOBAL source + swizzled ds_read
// (rule 21). setprio(1) around each 16-MFMA cluster (T5).
__global__ void __launch_bounds__(512, 2) gemm_bt_kernel(
    const void* __restrict__ xraw,
    const void* __restrict__ bias_candA, const void* __restrict__ bias_candB,
    void* __restrict__ outraw)
{
    // A: [3][256][64] bf16 = 96 KiB ; B: [3][128][64] bf16 = 48 KiB ; total 144 KiB
    __shared__ __attribute__((aligned(128))) __bf16 sm[3 * BM * BK + 3 * BN * BK];
    const int SB = 3 * BM * BK;                 // element base of B region

    const int mode = g_flags[0];
    const void* bias_raw = g_flags[1] ? bias_candA : bias_candB; // perm==B -> bias==A
    const __bf16* __restrict__ Xp = (mode == 0) ? (const __bf16*)xraw : g_X;
    const __bf16* __restrict__ Bt = g_Bt;

    const int tid  = threadIdx.x;
    const int wave = tid >> 6;
    const int lane = tid & 63;

    // XCD-aware bijective swizzle: nwg = 32*32 = 1024, divisible by 8
    const int orig = blockIdx.y * 32 + blockIdx.x;
    const int swz  = (orig & 7) * (1024 >> 3) + (orig >> 3);
    const int bn0  = (swz & 31) * BN;
    const int bm0  = (swz >> 5) * BM;

    // ---- staging geometry (per gload: one wave covers 8 rows x 64 k = 1 KiB) ----
    const int lrow8 = lane >> 3;                        // row within 8-row chunk
    const int ksw   = ((lane & 7) ^ lrow8) << 3;        // inverse-swizzled global k offs (elems)
    const size_t aoff = (size_t)(bm0 + wave * 32 + lrow8) * K_DIM + ksw;
    const size_t boff = (size_t)(bn0 + wave * 16 + lrow8) * K_DIM + ksw;
    const int aldsb = (wave * 4) * 512;                 // wave's A chunk-0 base (elems)
    const int bldsb = (wave * 2) * 512;                 // wave's B chunk-0 base (elems)

    // ---- fragment geometry ----
    const int wm   = (wave >> 1) << 6;                  // 0,64,128,192 (M)
    const int wn   = (wave & 1) << 6;                   // 0,64 (N)
    const int frow = lane & 15;
    const int fk   = (lane >> 4) << 3;                  // 0,8,16,24
    const int ksw8 = (lane & 7) << 3;                   // read-side swizzle XOR (elems)

    floatx4 acc[4][4] = {};

    // ---- prologue: stage tiles 0,1 into buffers 0,1 (12 loads), wait oldest 6 ----
#pragma unroll
    for (int tt = 0; tt < 2; ++tt) {
#pragma unroll
        for (int c = 0; c < 4; ++c)
            global_to_lds16(Xp + aoff + (size_t)c * (8 * K_DIM) + tt * BK,
                            &sm[tt * (BM * BK) + aldsb + c * 512]);
#pragma unroll
        for (int c = 0; c < 2; ++c)
            global_to_lds16(Bt + boff + (size_t)c * (8 * K_DIM) + tt * BK,
                            &sm[SB + tt * (BN * BK) + bldsb + c * 512]);
    }
    asm volatile("s_waitcnt vmcnt(6)" ::: "memory");    // tile0 resident; tile1 in flight
    LDS_FENCE();
    __builtin_amdgcn_s_barrier();
    LDS_FENCE();

    int cur = 0;
#pragma unroll 1
    for (int t = 0; t < NT; ++t) {
        int nb = cur + 2; if (nb >= 3) nb -= 3;
        const int curA = cur * (BM * BK);
        const int curB = SB + cur * (BN * BK);
        const bool stage = (t + 2 < NT);
        const int kt2 = (t + 2) * BK;

#pragma unroll
        for (int ks = 0; ks < 2; ++ks) {
            // phase: 8 swizzled ds_read_b128  ||  3 global_load_lds  ||  16 MFMA
            bf16x8 a[4], b[4];
            const int kb = (ks * 32 + fk) ^ ksw8;
#pragma unroll
            for (int i = 0; i < 4; ++i)
                a[i] = *(const bf16x8*)&sm[curA + (wm + i * 16 + frow) * 64 + kb];
#pragma unroll
            for (int j = 0; j < 4; ++j)
                b[j] = *(const bf16x8*)&sm[curB + (wn + j * 16 + frow) * 64 + kb];

            if (stage) {
                if (ks == 0) {
#pragma unroll
                    for (int c = 0; c < 3; ++c)
                        global_to_lds16(Xp + aoff + (size_t)c * (8 * K_DIM) + kt2,
                                        &sm[nb * (BM * BK) + aldsb + c * 512]);
                } else {
                    global_to_lds16(Xp + aoff + (size_t)3 * (8 * K_DIM) + kt2,
                                    &sm[nb * (BM * BK) + aldsb + 3 * 512]);
#pragma unroll
                    for (int c = 0; c < 2; ++c)
                        global_to_lds16(Bt + boff + (size_t)c * (8 * K_DIM) + kt2,
                                        &sm[SB + nb * (BN * BK) + bldsb + c * 512]);
                }
            }
            if (ks == 1) {
                // counted wait: tile t+1's 6 loads done; tile t+2's 6 stay in flight
                if (stage) asm volatile("s_waitcnt vmcnt(6)" ::: "memory");
                else       asm volatile("s_waitcnt vmcnt(0)" ::: "memory"); // drain tail
            }
            LDS_FENCE();
            __builtin_amdgcn_s_barrier();
            LDS_FENCE();

            __builtin_amdgcn_s_setprio(1);
#pragma unroll
            for (int i = 0; i < 4; ++i)
#pragma unroll
                for (int j = 0; j < 4; ++j)
                    acc[i][j] = __builtin_amdgcn_mfma_f32_16x16x32_bf16(
                        a[i], b[j], acc[i][j], 0, 0, 0);
            __builtin_amdgcn_s_setprio(0);

            LDS_FENCE();
            __builtin_amdgcn_s_barrier();
            LDS_FENCE();
        }
        cur = cur + 1; if (cur >= 3) cur = 0;
    }

    // Epilogue: C/D layout col=lane&15, row=(lane>>4)*4+reg  [m89-verified]
    const int ccol = lane & 15;
    const int crow = (lane >> 4) << 2;
#pragma unroll
    for (int j = 0; j < 4; ++j) {
        const int col = bn0 + wn + j * 16 + ccol;
        float bv;
        if (mode == 1)      bv = ((const float*)bias_raw)[col];
        else if (mode == 2) bv = (float)((const _Float16*)bias_raw)[col];
        else                bv = (float)((const __bf16*)bias_raw)[col];
#pragma unroll
        for (int i = 0; i < 4; ++i) {
            const int row = bm0 + wm + i * 16 + crow;
#pragma unroll
            for (int r = 0; r < 4; ++r) {
                float v = acc[i][j][r] + bv;
                size_t idx = (size_t)(row + r) * N_DIM + col;
                if (mode == 1)      ((float*)outraw)[idx] = v;
                else if (mode == 2) ((_Float16*)outraw)[idx] = (_Float16)v;
                else                ((__bf16*)outraw)[idx] = (__bf16)v;
            }
        }
    }
}

extern "C" void kernel_launch(void* const* d_in, const int* in_sizes, int n_in,
                              void* d_out, int out_size, void* d_ws, size_t ws_size,
                              hipStream_t stream) {
    // Map inputs by element count (round-5 lesson: d_in is NOT in dict order).
    int idx_x = 0, idx_qw = 1, idx_qs = 2, idx_qsm = 3, idx_a = -1, idx_b = -1;
    for (int i = 0; i < n_in; ++i) {
        switch (in_sizes[i]) {
            case 33554432: idx_x = i; break;                       // x [8192][4096]
            case 2097152:  idx_qw = i; break;                      // q_weight [512][4096]
            case 16384:    idx_qs = i; break;                      // q_scale [32][512]
            case 32:       idx_qsm = i; break;                     // q_scale_max [32]
            case 4096:     (idx_a < 0 ? idx_a : idx_b) = i; break; // q_invperm / bias
            default: break;
        }
    }
    if (idx_a < 0) idx_a = 4;
    if (idx_b < 0) idx_b = 5;

    const void* xraw  = d_in[idx_x];
    const int*  qw    = (const int*)d_in[idx_qw];
    const int*  qs    = (const int*)d_in[idx_qs];
    const void* qsm   = d_in[idx_qsm];
    const int*  candA = (const int*)d_in[idx_a];
    const int*  candB = (const int*)d_in[idx_b];

    probe_kernel<<<1, 256, 0, stream>>>(xraw, candA, candB);
    convert_x_kernel<<<2048, 256, 0, stream>>>(xraw);
    dim3 dqg(N_DIM / 16, (K_DIM / 8) / 16);
    dequant_perm_kernel<<<dqg, 256, 0, stream>>>(qw, qs, qsm, candA, candB);
    dim3 grid(N_DIM / BN, M_DIM / BM);   // (32, 32)
    gemm_bt_kernel<<<grid, 512, 0, stream>>>(xraw, d_in[idx_a], d_in[idx_b], d_out);
}